// Round 1
// baseline (1085.178 us; speedup 1.0000x reference)
//
#include <hip/hip_runtime.h>

#define TOK  16384
#define NEXP 8
#define DIM  1024
#define DDIM 4096
#define KCAP 2048

typedef float  floatx4 __attribute__((ext_vector_type(4)));
typedef short  shortx8 __attribute__((ext_vector_type(8)));

static __device__ __forceinline__ unsigned short f2bf(float x) {
  unsigned u = __float_as_uint(x);
  return (unsigned short)((u + 0x7fffu + ((u >> 16) & 1u)) >> 16);
}

// ---------------- fp32 -> bf16 weight convert ----------------
__global__ __launch_bounds__(256) void cvt_kernel(const float* __restrict__ src,
                                                  unsigned short* __restrict__ dst, int n4) {
  int i = blockIdx.x * 256 + threadIdx.x;
  if (i < n4) {
    float4 v = ((const float4*)src)[i];
    ushort4 o = make_ushort4(f2bf(v.x), f2bf(v.y), f2bf(v.z), f2bf(v.w));
    ((ushort4*)dst)[i] = o;
  }
}

// ---------------- gating: logits + softmax ----------------
__global__ __launch_bounds__(256) void gate_kernel(const float* __restrict__ x,
                                                   const float* __restrict__ gw,
                                                   float* __restrict__ scores) {
  __shared__ float gws[NEXP * DIM];
  int tid = threadIdx.x;
  for (int i = tid; i < NEXP * DIM / 4; i += 256)
    ((float4*)gws)[i] = ((const float4*)gw)[i];
  __syncthreads();
  int wave = tid >> 6, lane = tid & 63;
  int t = blockIdx.x * 4 + wave;
  const float4* xr = (const float4*)(x + (size_t)t * DIM);
  float4 xv[4];
#pragma unroll
  for (int j = 0; j < 4; ++j) xv[j] = xr[j * 64 + lane];
  float acc[NEXP];
#pragma unroll
  for (int e = 0; e < NEXP; ++e) acc[e] = 0.f;
#pragma unroll
  for (int e = 0; e < NEXP; ++e) {
    const float4* g4 = (const float4*)(gws + e * DIM);
#pragma unroll
    for (int j = 0; j < 4; ++j) {
      float4 g = g4[j * 64 + lane];
      acc[e] += xv[j].x * g.x + xv[j].y * g.y + xv[j].z * g.z + xv[j].w * g.w;
    }
  }
#pragma unroll
  for (int off = 32; off > 0; off >>= 1) {
#pragma unroll
    for (int e = 0; e < NEXP; ++e) acc[e] += __shfl_down(acc[e], off);
  }
  if (lane == 0) {
    float mx = acc[0];
#pragma unroll
    for (int e = 1; e < NEXP; ++e) mx = fmaxf(mx, acc[e]);
    float ex[NEXP], sum = 0.f;
#pragma unroll
    for (int e = 0; e < NEXP; ++e) { ex[e] = expf(acc[e] - mx); sum += ex[e]; }
    float inv = 1.f / sum;
#pragma unroll
    for (int e = 0; e < NEXP; ++e) scores[(size_t)e * TOK + t] = ex[e] * inv;
  }
}

// ---------------- per-expert exact top-k set (lowest-index tie-break) ----------------
__global__ __launch_bounds__(256) void topk_kernel(const float* __restrict__ scores,
                                                   int* __restrict__ sel,
                                                   float* __restrict__ selw) {
  int e = blockIdx.x;
  const float* s = scores + (size_t)e * TOK;
  int tid = threadIdx.x, lane = tid & 63, wave = tid >> 6;
  __shared__ int cnt;
  __shared__ int wsum[4];

  // radix binary search for T = k-th largest (positive floats order as uint bits)
  unsigned prefix = 0;
  for (int bit = 30; bit >= 0; --bit) {
    unsigned cand = prefix | (1u << bit);
    if (tid == 0) cnt = 0;
    __syncthreads();
    int c = 0;
    for (int i = tid; i < TOK; i += 256) c += (__float_as_uint(s[i]) >= cand) ? 1 : 0;
#pragma unroll
    for (int off = 32; off > 0; off >>= 1) c += __shfl_down(c, off);
    if (lane == 0) atomicAdd(&cnt, c);
    __syncthreads();
    if (cnt >= KCAP) prefix = cand;
    __syncthreads();
  }
  unsigned T = prefix;

  // count strictly greater
  if (tid == 0) cnt = 0;
  __syncthreads();
  {
    int c = 0;
    for (int i = tid; i < TOK; i += 256) c += (__float_as_uint(s[i]) > T) ? 1 : 0;
#pragma unroll
    for (int off = 32; off > 0; off >>= 1) c += __shfl_down(c, off);
    if (lane == 0) atomicAdd(&cnt, c);
  }
  __syncthreads();
  int n_gt = cnt;
  int need = KCAP - n_gt;

  __shared__ int pos;
  __shared__ int tiebase;
  if (tid == 0) { pos = 0; tiebase = 0; }
  __syncthreads();
  for (int chunk = 0; chunk < TOK; chunk += 256) {
    int i = chunk + tid;
    unsigned v = __float_as_uint(s[i]);
    if (v > T) {
      int p = atomicAdd(&pos, 1);
      sel[e * KCAP + p]  = i;
      selw[e * KCAP + p] = __uint_as_float(v);
    }
    bool tie = (v == T);
    unsigned long long m = __ballot(tie);
    if (lane == 0) wsum[wave] = __popcll(m);
    __syncthreads();
    int base = tiebase;
    for (int w = 0; w < wave; ++w) base += wsum[w];
    int rank = base + __popcll(m & ((1ull << lane) - 1ull));
    if (tie && rank < need) {
      sel[e * KCAP + n_gt + rank]  = i;
      selw[e * KCAP + n_gt + rank] = __uint_as_float(T);
    }
    __syncthreads();
    if (tid == 0) tiebase += wsum[0] + wsum[1] + wsum[2] + wsum[3];
    __syncthreads();
  }
}

// ---------------- gather selected tokens + layernorm -> bf16 Y ----------------
__global__ __launch_bounds__(256) void gather_ln_kernel(const float* __restrict__ x,
                                                        const int* __restrict__ sel,
                                                        const float* __restrict__ lnw,
                                                        const float* __restrict__ lnb,
                                                        unsigned short* __restrict__ Y) {
  int e = blockIdx.y, i = blockIdx.x;
  int tid = threadIdx.x, lane = tid & 63, wave = tid >> 6;
  int t = sel[e * KCAP + i];
  const float4* xr = (const float4*)(x + (size_t)t * DIM);
  float4 v = xr[tid];
  float s  = v.x + v.y + v.z + v.w;
  float sq = v.x * v.x + v.y * v.y + v.z * v.z + v.w * v.w;
#pragma unroll
  for (int off = 32; off > 0; off >>= 1) { s += __shfl_down(s, off); sq += __shfl_down(sq, off); }
  __shared__ float red[8];
  if (lane == 0) { red[wave] = s; red[4 + wave] = sq; }
  __syncthreads();
  s  = red[0] + red[1] + red[2] + red[3];
  sq = red[4] + red[5] + red[6] + red[7];
  float mu  = s * (1.f / DIM);
  float var = sq * (1.f / DIM) - mu * mu;
  float rs  = rsqrtf(var + 1e-5f);
  float4 w = ((const float4*)lnw)[tid];
  float4 b = ((const float4*)lnb)[tid];
  ushort4 o = make_ushort4(f2bf((v.x - mu) * rs * w.x + b.x),
                           f2bf((v.y - mu) * rs * w.y + b.y),
                           f2bf((v.z - mu) * rs * w.z + b.z),
                           f2bf((v.w - mu) * rs * w.w + b.w));
  ((ushort4*)(Y + ((size_t)e * KCAP + i) * DIM))[tid] = o;
}

// ---------------- bf16 MFMA GEMM, 128x128 tile, BK=64, global_load_lds staging ----------------
// MODE 1: H = gelu(A @ B^T + bias)   (bf16 out, per-expert)
// MODE 2: Out[sel[row]] += selw[row] * (A @ B^T + bias)   (fp32 atomic scatter)
#define BM  128
#define BN  128
#define BKT 64

template <int MODE>
__global__ __launch_bounds__(256) void gemm_kernel(
    const unsigned short* __restrict__ Aall,   // per-expert M x K (bf16, K-contig)
    const unsigned short* __restrict__ Ball,   // per-expert N x K (bf16, K-contig)
    const float* __restrict__ biasAll,         // per-expert N
    int M, int N, int K,
    unsigned short* __restrict__ Hall,         // MODE 1
    float* __restrict__ Out,                   // MODE 2
    const int* __restrict__ sel, const float* __restrict__ selw) {
  int e = blockIdx.z;
  const unsigned short* A = Aall + (size_t)e * M * K;
  const unsigned short* B = Ball + (size_t)e * N * K;
  const float* bias = biasAll + (size_t)e * N;

  __shared__ __align__(16) unsigned short As[BM * BKT];
  __shared__ __align__(16) unsigned short Bs[BN * BKT];
  __shared__ int   selS[BM];
  __shared__ float wS[BM];

  int tid = threadIdx.x, lane = tid & 63, wave = tid >> 6;
  int m0 = blockIdx.y * BM, n0 = blockIdx.x * BN;
  if (MODE == 2 && tid < BM) {
    selS[tid] = sel[e * KCAP + m0 + tid];
    wS[tid]   = selw[e * KCAP + m0 + tid];
  }
  int wm = (wave & 1) * 64, wn = (wave >> 1) * 64;
  int srow = lane >> 3;          // staging: row within 8-row group
  int scol = (lane & 7) * 8;     // staging: col (elements), 16B granules
  int row = lane & 15, quad = lane >> 4;

  floatx4 acc[4][4];
  floatx4 zero = {0.f, 0.f, 0.f, 0.f};
#pragma unroll
  for (int a = 0; a < 4; ++a)
#pragma unroll
    for (int b = 0; b < 4; ++b) acc[a][b] = zero;

  for (int k0 = 0; k0 < K; k0 += BKT) {
    __syncthreads();
#pragma unroll
    for (int j = 0; j < 4; ++j) {
      int q = wave * 4 + j;
      const unsigned short* ga = A + (size_t)(m0 + q * 8 + srow) * K + k0 + scol;
      __builtin_amdgcn_global_load_lds((const __attribute__((address_space(1))) void*)ga,
                                       (__attribute__((address_space(3))) void*)(As + q * 512),
                                       16, 0, 0);
      const unsigned short* gb = B + (size_t)(n0 + q * 8 + srow) * K + k0 + scol;
      __builtin_amdgcn_global_load_lds((const __attribute__((address_space(1))) void*)gb,
                                       (__attribute__((address_space(3))) void*)(Bs + q * 512),
                                       16, 0, 0);
    }
    __syncthreads();
#pragma unroll
    for (int kk = 0; kk < BKT; kk += 32) {
      shortx8 af[4], bf[4];
#pragma unroll
      for (int ti = 0; ti < 4; ++ti)
        af[ti] = *(const shortx8*)&As[(wm + ti * 16 + row) * BKT + kk + quad * 8];
#pragma unroll
      for (int tj = 0; tj < 4; ++tj)
        bf[tj] = *(const shortx8*)&Bs[(wn + tj * 16 + row) * BKT + kk + quad * 8];
#pragma unroll
      for (int ti = 0; ti < 4; ++ti)
#pragma unroll
        for (int tj = 0; tj < 4; ++tj)
          acc[ti][tj] = __builtin_amdgcn_mfma_f32_16x16x32_bf16(af[ti], bf[tj], acc[ti][tj], 0, 0, 0);
    }
  }

  // epilogue: C/D layout col=lane&15, row=quad*4+reg  [m89/m91-verified]
#pragma unroll
  for (int ti = 0; ti < 4; ++ti) {
#pragma unroll
    for (int tj = 0; tj < 4; ++tj) {
      int gn = n0 + wn + tj * 16 + row;
      float bb = bias[gn];
#pragma unroll
      for (int r = 0; r < 4; ++r) {
        int lrow = wm + ti * 16 + quad * 4 + r;
        float v = acc[ti][tj][r] + bb;
        if (MODE == 1) {
          float u = 0.7978845608028654f * (v + 0.044715f * v * v * v);
          u = fminf(u, 15.f);                       // overflow guard; tanh(15)==1
          float e2 = __expf(2.f * u);
          float th = __fdividef(e2 - 1.f, e2 + 1.f);
          float g = 0.5f * v * (1.f + th);
          Hall[(size_t)e * M * N + (size_t)(m0 + lrow) * N + gn] = f2bf(g);
        } else {
          atomicAdd(&Out[(size_t)selS[lrow] * DIM + gn], wS[lrow] * v);
        }
      }
    }
  }
}

extern "C" void kernel_launch(void* const* d_in, const int* in_sizes, int n_in,
                              void* d_out, int out_size, void* d_ws, size_t ws_size,
                              hipStream_t stream) {
  const float* x   = (const float*)d_in[0];
  const float* gw  = (const float*)d_in[1];
  const float* lnw = (const float*)d_in[2];
  const float* lnb = (const float*)d_in[3];
  const float* fc1 = (const float*)d_in[4];
  const float* b1  = (const float*)d_in[5];
  const float* fc2 = (const float*)d_in[6];
  const float* b2  = (const float*)d_in[7];
  float* out = (float*)d_out;

  char* p = (char*)d_ws;
  float* scores = (float*)p;                 p += (size_t)NEXP * TOK * 4;     // 512 KB
  int*   sel    = (int*)p;                   p += (size_t)NEXP * KCAP * 4;    // 64 KB
  float* selw   = (float*)p;                 p += (size_t)NEXP * KCAP * 4;    // 64 KB
  unsigned short* Wb = (unsigned short*)p;   p += (size_t)NEXP * DDIM * DIM * 2; // 64 MB (fc1 then fc2)
  unsigned short* Y  = (unsigned short*)p;   p += (size_t)NEXP * KCAP * DIM * 2; // 32 MB
  unsigned short* H  = (unsigned short*)p;   p += (size_t)NEXP * KCAP * DDIM * 2; // 128 MB

  // out = x (scatter-add base)
  hipMemcpyAsync(out, x, (size_t)TOK * DIM * sizeof(float), hipMemcpyDeviceToDevice, stream);

  // gating + selection + LN gather
  gate_kernel<<<TOK / 4, 256, 0, stream>>>(x, gw, scores);
  topk_kernel<<<NEXP, 256, 0, stream>>>(scores, sel, selw);
  gather_ln_kernel<<<dim3(KCAP, NEXP), 256, 0, stream>>>(x, sel, lnw, lnb, Y);

  // GEMM1: H = gelu(Y @ fc1^T + b1)
  const int n4w = NEXP * DDIM * DIM / 4;
  cvt_kernel<<<n4w / 256, 256, 0, stream>>>(fc1, Wb, n4w);
  gemm_kernel<1><<<dim3(DDIM / BN, KCAP / BM, NEXP), 256, 0, stream>>>(
      Y, Wb, b1, KCAP, DDIM, DIM, H, nullptr, nullptr, nullptr);

  // GEMM2: out[sel] += selw * (H @ fc2^T + b2)   (Wb reused for fc2)
  cvt_kernel<<<n4w / 256, 256, 0, stream>>>(fc2, Wb, n4w);
  gemm_kernel<2><<<dim3(DIM / BN, KCAP / BM, NEXP), 256, 0, stream>>>(
      H, Wb, b2, KCAP, DIM, DDIM, nullptr, out, sel, selw);
}

// Round 2
// 926.894 us; speedup vs baseline: 1.1708x; 1.1708x over previous
//
#include <hip/hip_runtime.h>

#define TOK  16384
#define NEXP 8
#define DIM  1024
#define DDIM 4096
#define KCAP 2048

typedef float  floatx4 __attribute__((ext_vector_type(4)));
typedef short  shortx8 __attribute__((ext_vector_type(8)));

static __device__ __forceinline__ unsigned short f2bf(float x) {
  unsigned u = __float_as_uint(x);
  return (unsigned short)((u + 0x7fffu + ((u >> 16) & 1u)) >> 16);
}

// ---------------- fp32 -> bf16 weight convert ----------------
__global__ __launch_bounds__(256) void cvt_kernel(const float* __restrict__ src,
                                                  unsigned short* __restrict__ dst, int n4) {
  int i = blockIdx.x * 256 + threadIdx.x;
  if (i < n4) {
    float4 v = ((const float4*)src)[i];
    ushort4 o = make_ushort4(f2bf(v.x), f2bf(v.y), f2bf(v.z), f2bf(v.w));
    ((ushort4*)dst)[i] = o;
  }
}

// ---------------- gating: logits + softmax ----------------
__global__ __launch_bounds__(256) void gate_kernel(const float* __restrict__ x,
                                                   const float* __restrict__ gw,
                                                   float* __restrict__ scores) {
  __shared__ float gws[NEXP * DIM];
  int tid = threadIdx.x;
  for (int i = tid; i < NEXP * DIM / 4; i += 256)
    ((float4*)gws)[i] = ((const float4*)gw)[i];
  __syncthreads();
  int wave = tid >> 6, lane = tid & 63;
  int t = blockIdx.x * 4 + wave;
  const float4* xr = (const float4*)(x + (size_t)t * DIM);
  float4 xv[4];
#pragma unroll
  for (int j = 0; j < 4; ++j) xv[j] = xr[j * 64 + lane];
  float acc[NEXP];
#pragma unroll
  for (int e = 0; e < NEXP; ++e) acc[e] = 0.f;
#pragma unroll
  for (int e = 0; e < NEXP; ++e) {
    const float4* g4 = (const float4*)(gws + e * DIM);
#pragma unroll
    for (int j = 0; j < 4; ++j) {
      float4 g = g4[j * 64 + lane];
      acc[e] += xv[j].x * g.x + xv[j].y * g.y + xv[j].z * g.z + xv[j].w * g.w;
    }
  }
#pragma unroll
  for (int off = 32; off > 0; off >>= 1) {
#pragma unroll
    for (int e = 0; e < NEXP; ++e) acc[e] += __shfl_down(acc[e], off);
  }
  if (lane == 0) {
    float mx = acc[0];
#pragma unroll
    for (int e = 1; e < NEXP; ++e) mx = fmaxf(mx, acc[e]);
    float ex[NEXP], sum = 0.f;
#pragma unroll
    for (int e = 0; e < NEXP; ++e) { ex[e] = expf(acc[e] - mx); sum += ex[e]; }
    float inv = 1.f / sum;
#pragma unroll
    for (int e = 0; e < NEXP; ++e) scores[(size_t)e * TOK + t] = ex[e] * inv;
  }
}

// ---------------- per-expert exact top-k set (lowest-index tie-break) ----------------
#define TKT 1024
#define TKW (TKT / 64)
__global__ __launch_bounds__(TKT) void topk_kernel(const float* __restrict__ scores,
                                                   int* __restrict__ sel,
                                                   float* __restrict__ selw) {
  int e = blockIdx.x;
  const float* s = scores + (size_t)e * TOK;
  int tid = threadIdx.x, lane = tid & 63, wave = tid >> 6;
  __shared__ int cnt;
  __shared__ int wsum[TKW];

  // radix binary search for T = k-th largest (positive floats order as uint bits)
  unsigned prefix = 0;
  for (int bit = 30; bit >= 0; --bit) {
    unsigned cand = prefix | (1u << bit);
    if (tid == 0) cnt = 0;
    __syncthreads();
    int c = 0;
    for (int i = tid; i < TOK; i += TKT) c += (__float_as_uint(s[i]) >= cand) ? 1 : 0;
#pragma unroll
    for (int off = 32; off > 0; off >>= 1) c += __shfl_down(c, off);
    if (lane == 0) atomicAdd(&cnt, c);
    __syncthreads();
    if (cnt >= KCAP) prefix = cand;
    __syncthreads();
  }
  unsigned T = prefix;

  // count strictly greater
  if (tid == 0) cnt = 0;
  __syncthreads();
  {
    int c = 0;
    for (int i = tid; i < TOK; i += TKT) c += (__float_as_uint(s[i]) > T) ? 1 : 0;
#pragma unroll
    for (int off = 32; off > 0; off >>= 1) c += __shfl_down(c, off);
    if (lane == 0) atomicAdd(&cnt, c);
  }
  __syncthreads();
  int n_gt = cnt;
  int need = KCAP - n_gt;

  __shared__ int pos;
  __shared__ int tiebase;
  if (tid == 0) { pos = 0; tiebase = 0; }
  __syncthreads();
  for (int chunk = 0; chunk < TOK; chunk += TKT) {
    int i = chunk + tid;
    unsigned v = __float_as_uint(s[i]);
    if (v > T) {
      int p = atomicAdd(&pos, 1);
      sel[e * KCAP + p]  = i;
      selw[e * KCAP + p] = __uint_as_float(v);
    }
    bool tie = (v == T);
    unsigned long long m = __ballot(tie);
    if (lane == 0) wsum[wave] = __popcll(m);
    __syncthreads();
    int base = tiebase;
    for (int w = 0; w < wave; ++w) base += wsum[w];
    int rank = base + __popcll(m & ((1ull << lane) - 1ull));
    if (tie && rank < need) {
      sel[e * KCAP + n_gt + rank]  = i;
      selw[e * KCAP + n_gt + rank] = __uint_as_float(T);
    }
    __syncthreads();
    if (tid == 0) {
      int tb = 0;
#pragma unroll
      for (int w = 0; w < TKW; ++w) tb += wsum[w];
      tiebase += tb;
    }
    __syncthreads();
  }
}

// ---------------- gather selected tokens + layernorm -> bf16 Y ----------------
__global__ __launch_bounds__(256) void gather_ln_kernel(const float* __restrict__ x,
                                                        const int* __restrict__ sel,
                                                        const float* __restrict__ lnw,
                                                        const float* __restrict__ lnb,
                                                        unsigned short* __restrict__ Y) {
  int e = blockIdx.y, i = blockIdx.x;
  int tid = threadIdx.x, lane = tid & 63, wave = tid >> 6;
  int t = sel[e * KCAP + i];
  const float4* xr = (const float4*)(x + (size_t)t * DIM);
  float4 v = xr[tid];
  float s  = v.x + v.y + v.z + v.w;
  float sq = v.x * v.x + v.y * v.y + v.z * v.z + v.w * v.w;
#pragma unroll
  for (int off = 32; off > 0; off >>= 1) { s += __shfl_down(s, off); sq += __shfl_down(sq, off); }
  __shared__ float red[8];
  if (lane == 0) { red[wave] = s; red[4 + wave] = sq; }
  __syncthreads();
  s  = red[0] + red[1] + red[2] + red[3];
  sq = red[4] + red[5] + red[6] + red[7];
  float mu  = s * (1.f / DIM);
  float var = sq * (1.f / DIM) - mu * mu;
  float rs  = rsqrtf(var + 1e-5f);
  float4 w = ((const float4*)lnw)[tid];
  float4 b = ((const float4*)lnb)[tid];
  ushort4 o = make_ushort4(f2bf((v.x - mu) * rs * w.x + b.x),
                           f2bf((v.y - mu) * rs * w.y + b.y),
                           f2bf((v.z - mu) * rs * w.z + b.z),
                           f2bf((v.w - mu) * rs * w.w + b.w));
  ((ushort4*)(Y + ((size_t)e * KCAP + i) * DIM))[tid] = o;
}

// ---------------- bf16 MFMA GEMM, 128x128 tile, BK=64, global_load_lds staging ----------------
// XOR-swizzled LDS layout: element (row R, granule g of 8 shorts) lives at
// LDS offset R*64 + ((g ^ (R&7))*8). Staging implements the permutation on the
// GLOBAL read side (lane j8 of row r8 reads global granule j8^r8) so the
// wave-uniform-base+lane*16 LDS write of global_load_lds stays linear.
// Result: fragment ds_read_b128 hits each bank exactly 2x per wave (free),
// instead of 16-way conflicts from the 128B row stride.
// MODE 1: H = gelu(A @ B^T + bias)   (bf16 out, per-expert)
// MODE 2: Out[sel[row]] += selw[row] * (A @ B^T + bias)   (fp32 atomic scatter)
#define BM  128
#define BN  128
#define BKT 64

template <int MODE>
__global__ __launch_bounds__(256) void gemm_kernel(
    const unsigned short* __restrict__ Aall,   // per-expert M x K (bf16, K-contig)
    const unsigned short* __restrict__ Ball,   // per-expert N x K (bf16, K-contig)
    const float* __restrict__ biasAll,         // per-expert N
    int M, int N, int K,
    unsigned short* __restrict__ Hall,         // MODE 1
    float* __restrict__ Out,                   // MODE 2
    const int* __restrict__ sel, const float* __restrict__ selw) {
  int e = blockIdx.z;
  const unsigned short* A = Aall + (size_t)e * M * K;
  const unsigned short* B = Ball + (size_t)e * N * K;
  const float* bias = biasAll + (size_t)e * N;

  __shared__ __align__(16) unsigned short As[BM * BKT];
  __shared__ __align__(16) unsigned short Bs[BN * BKT];
  __shared__ int   selS[BM];
  __shared__ float wS[BM];

  int tid = threadIdx.x, lane = tid & 63, wave = tid >> 6;
  int m0 = blockIdx.y * BM, n0 = blockIdx.x * BN;
  if (MODE == 2 && tid < BM) {
    selS[tid] = sel[e * KCAP + m0 + tid];
    wS[tid]   = selw[e * KCAP + m0 + tid];
  }
  int wm = (wave & 1) * 64, wn = (wave >> 1) * 64;
  int r8 = lane >> 3;                 // staging: row within 8-row group
  int j8 = lane & 7;
  int scol = (j8 ^ r8) * 8;           // staging: swizzled global col (elements)
  int row = lane & 15, quad = lane >> 4;
  int r7 = row & 7;

  floatx4 acc[4][4];
  floatx4 zero = {0.f, 0.f, 0.f, 0.f};
#pragma unroll
  for (int a = 0; a < 4; ++a)
#pragma unroll
    for (int b = 0; b < 4; ++b) acc[a][b] = zero;

  for (int k0 = 0; k0 < K; k0 += BKT) {
    __syncthreads();
#pragma unroll
    for (int j = 0; j < 4; ++j) {
      int q = wave * 4 + j;
      const unsigned short* ga = A + (size_t)(m0 + q * 8 + r8) * K + k0 + scol;
      __builtin_amdgcn_global_load_lds((const __attribute__((address_space(1))) void*)ga,
                                       (__attribute__((address_space(3))) void*)(As + q * 512),
                                       16, 0, 0);
      const unsigned short* gb = B + (size_t)(n0 + q * 8 + r8) * K + k0 + scol;
      __builtin_amdgcn_global_load_lds((const __attribute__((address_space(1))) void*)gb,
                                       (__attribute__((address_space(3))) void*)(Bs + q * 512),
                                       16, 0, 0);
    }
    __syncthreads();
#pragma unroll
    for (int kk = 0; kk < BKT; kk += 32) {
      int xg = ((quad + (kk >> 3)) ^ r7) << 3;   // swizzled granule offset (elements)
      shortx8 af[4], bf[4];
#pragma unroll
      for (int ti = 0; ti < 4; ++ti)
        af[ti] = *(const shortx8*)&As[(wm + ti * 16 + row) * BKT + xg];
#pragma unroll
      for (int tj = 0; tj < 4; ++tj)
        bf[tj] = *(const shortx8*)&Bs[(wn + tj * 16 + row) * BKT + xg];
#pragma unroll
      for (int ti = 0; ti < 4; ++ti)
#pragma unroll
        for (int tj = 0; tj < 4; ++tj)
          acc[ti][tj] = __builtin_amdgcn_mfma_f32_16x16x32_bf16(af[ti], bf[tj], acc[ti][tj], 0, 0, 0);
    }
  }

  // epilogue: C/D layout col=lane&15, row=quad*4+reg  [m89/m91-verified]
#pragma unroll
  for (int ti = 0; ti < 4; ++ti) {
#pragma unroll
    for (int tj = 0; tj < 4; ++tj) {
      int gn = n0 + wn + tj * 16 + row;
      float bb = bias[gn];
#pragma unroll
      for (int r = 0; r < 4; ++r) {
        int lrow = wm + ti * 16 + quad * 4 + r;
        float v = acc[ti][tj][r] + bb;
        if (MODE == 1) {
          float u = 0.7978845608028654f * (v + 0.044715f * v * v * v);
          u = fminf(u, 15.f);                       // overflow guard; tanh(15)==1
          float e2 = __expf(2.f * u);
          float th = __fdividef(e2 - 1.f, e2 + 1.f);
          float g = 0.5f * v * (1.f + th);
          Hall[(size_t)e * M * N + (size_t)(m0 + lrow) * N + gn] = f2bf(g);
        } else {
          atomicAdd(&Out[(size_t)selS[lrow] * DIM + gn], wS[lrow] * v);
        }
      }
    }
  }
}

extern "C" void kernel_launch(void* const* d_in, const int* in_sizes, int n_in,
                              void* d_out, int out_size, void* d_ws, size_t ws_size,
                              hipStream_t stream) {
  const float* x   = (const float*)d_in[0];
  const float* gw  = (const float*)d_in[1];
  const float* lnw = (const float*)d_in[2];
  const float* lnb = (const float*)d_in[3];
  const float* fc1 = (const float*)d_in[4];
  const float* b1  = (const float*)d_in[5];
  const float* fc2 = (const float*)d_in[6];
  const float* b2  = (const float*)d_in[7];
  float* out = (float*)d_out;

  char* p = (char*)d_ws;
  float* scores = (float*)p;                 p += (size_t)NEXP * TOK * 4;     // 512 KB
  int*   sel    = (int*)p;                   p += (size_t)NEXP * KCAP * 4;    // 64 KB
  float* selw   = (float*)p;                 p += (size_t)NEXP * KCAP * 4;    // 64 KB
  unsigned short* Wb = (unsigned short*)p;   p += (size_t)NEXP * DDIM * DIM * 2; // 64 MB (fc1 then fc2)
  unsigned short* Y  = (unsigned short*)p;   p += (size_t)NEXP * KCAP * DIM * 2; // 32 MB
  unsigned short* H  = (unsigned short*)p;   p += (size_t)NEXP * KCAP * DDIM * 2; // 128 MB

  // out = x (scatter-add base)
  hipMemcpyAsync(out, x, (size_t)TOK * DIM * sizeof(float), hipMemcpyDeviceToDevice, stream);

  // gating + selection + LN gather
  gate_kernel<<<TOK / 4, 256, 0, stream>>>(x, gw, scores);
  topk_kernel<<<NEXP, TKT, 0, stream>>>(scores, sel, selw);
  gather_ln_kernel<<<dim3(KCAP, NEXP), 256, 0, stream>>>(x, sel, lnw, lnb, Y);

  // GEMM1: H = gelu(Y @ fc1^T + b1)
  const int n4w = NEXP * DDIM * DIM / 4;
  cvt_kernel<<<n4w / 256, 256, 0, stream>>>(fc1, Wb, n4w);
  gemm_kernel<1><<<dim3(DDIM / BN, KCAP / BM, NEXP), 256, 0, stream>>>(
      Y, Wb, b1, KCAP, DDIM, DIM, H, nullptr, nullptr, nullptr);

  // GEMM2: out[sel] += selw * (H @ fc2^T + b2)   (Wb reused for fc2)
  cvt_kernel<<<n4w / 256, 256, 0, stream>>>(fc2, Wb, n4w);
  gemm_kernel<2><<<dim3(DIM / BN, KCAP / BM, NEXP), 256, 0, stream>>>(
      H, Wb, b2, KCAP, DIM, DDIM, nullptr, out, sel, selw);
}